// Round 4
// baseline (303.949 us; speedup 1.0000x reference)
//
#include <hip/hip_runtime.h>
#include <math.h>

// ---------------- types / helpers ----------------
typedef short s16x8 __attribute__((ext_vector_type(8)));     // 8 bf16 in 4 VGPRs
typedef unsigned short u16;
typedef unsigned short u16x4 __attribute__((ext_vector_type(4)));
typedef float f32x4 __attribute__((ext_vector_type(4)));

__device__ __forceinline__ f32x4 mfma16(s16x8 a, s16x8 b, f32x4 c) {
  return __builtin_amdgcn_mfma_f32_16x16x32_bf16(a, b, c, 0, 0, 0);
}

// fp32 -> bf16 bits, round-to-nearest-even
__device__ __forceinline__ u16 f2bf(float f) {
  unsigned u = __builtin_bit_cast(unsigned, f);
  u = (u + 0x7fffu + ((u >> 16) & 1u)) >> 16;
  return (u16)u;
}

// pack two fp32 -> two truncated bf16 in one v_perm
__device__ __forceinline__ unsigned pk_trunc(float hi, float lo) {
  return __builtin_amdgcn_perm(__builtin_bit_cast(unsigned, hi),
                               __builtin_bit_cast(unsigned, lo), 0x07060302u);
}

// async global->LDS, 16B per lane; lds base wave-uniform, lane i lands at base + i*16
__device__ __forceinline__ void gll16(const void* g, void* l) {
  __builtin_amdgcn_global_load_lds((__attribute__((address_space(1))) void*)(void*)g,
                                   (__attribute__((address_space(3))) void*)l,
                                   16, 0, 0);
}

// wave-local LDS fence: drain DS queue + compiler ordering (no workgroup barrier)
__device__ __forceinline__ void lds_fence() {
  asm volatile("s_waitcnt lgkmcnt(0)" ::: "memory");
}

// ---------------- layout/convert kernels ----------------
__global__ __launch_bounds__(256) void k_convert_x(const float* __restrict__ x,
                                                   u16* __restrict__ xb) {
  int i = (blockIdx.x * 256 + threadIdx.x) * 8;
  const float4* xv = (const float4*)(x + i);
  float4 a = xv[0], b = xv[1];
  union { s16x8 v; u16 s[8]; } r;
  r.s[0] = f2bf(a.x); r.s[1] = f2bf(a.y); r.s[2] = f2bf(a.z); r.s[3] = f2bf(a.w);
  r.s[4] = f2bf(b.x); r.s[5] = f2bf(b.y); r.s[6] = f2bf(b.z); r.s[7] = f2bf(b.w);
  *(s16x8*)(xb + i) = r.v;
}

// in: fp32 [R][C]  ->  out: bf16 [C][R]
__global__ __launch_bounds__(256) void k_transpose_w(const float* __restrict__ in,
                                                     u16* __restrict__ out, int R, int C) {
  __shared__ float tile[32][33];
  int c0 = blockIdx.x * 32, r0 = blockIdx.y * 32;
  int tx = threadIdx.x & 31, ty = threadIdx.x >> 5;  // 32 x 8
#pragma unroll
  for (int s = 0; s < 4; ++s)
    tile[ty + 8 * s][tx] = in[(size_t)(r0 + ty + 8 * s) * C + c0 + tx];
  __syncthreads();
#pragma unroll
  for (int s = 0; s < 4; ++s)
    out[(size_t)(c0 + ty + 8 * s) * R + r0 + tx] = f2bf(tile[tx][ty + 8 * s]);
}

// v: bf16 [BH][2048][64] -> vt: bf16 [BH][64][2048]
__global__ __launch_bounds__(256) void k_transpose_v(const u16* __restrict__ v,
                                                     u16* __restrict__ vt) {
  __shared__ u16 tile[64][65];
  int bh = blockIdx.y, t0 = blockIdx.x * 64, tid = threadIdx.x;
#pragma unroll
  for (int p = 0; p < 16; ++p) {
    int idx = p * 256 + tid;
    int tt = idx >> 6, dd = idx & 63;
    tile[dd][tt] = v[((size_t)bh * 2048 + t0 + tt) * 64 + dd];
  }
  __syncthreads();
#pragma unroll
  for (int p = 0; p < 16; ++p) {
    int idx = p * 256 + tid;
    int dd = idx >> 6, tt = idx & 63;
    vt[((size_t)bh * 64 + dd) * 2048 + t0 + tt] = tile[dd][tt];
  }
}

// ---------------- GEMM: C = A[M,K] * Bt[N,K]^T + bias ----------------
// 1D grid, XCD-aware swizzle: xcd = id&7 (dispatch round-robin), each XCD owns an
// 8-mBlk strip (2 MB of A -> L2-resident) and sweeps nBlk. 64 mBlks in both GEMMs.
template <int EPI>
__global__ __launch_bounds__(256) void k_gemm(const u16* __restrict__ A,
                                              const u16* __restrict__ Bt,
                                              const float* __restrict__ bias,
                                              float* __restrict__ outp,
                                              u16* __restrict__ q_out,
                                              u16* __restrict__ k_out,
                                              u16* __restrict__ v_out,
                                              int K, int nIter) {
  __shared__ u16 As[4096];
  __shared__ u16 Bs[4096];
  int tid = threadIdx.x, w = tid >> 6, l = tid & 63;
  int r = l & 15, qd = l >> 4;
  int id = blockIdx.x;
  int xcd = id & 7, s0 = id >> 3;
  int mBlk = xcd * 8 + (s0 & 7);
  int nBlk = s0 >> 3;
  f32x4 acc[4][4] = {};

  const u16* ga[2]; const u16* gb[2]; u16* la[2]; u16* lb[2];
#pragma unroll
  for (int qq = 0; qq < 2; ++qq) {
    int grp = 2 * w + qq;
    int rowA = mBlk * 128 + grp * 16 + (l >> 2);
    int rowB = nBlk * 128 + grp * 16 + (l >> 2);
    int kcol = (l & 3) * 8;
    ga[qq] = A + (size_t)rowA * K + kcol;
    gb[qq] = Bt + (size_t)rowB * K + kcol;
    la[qq] = As + grp * 512;
    lb[qq] = Bs + grp * 512;
  }
  int aoff = ((w & 1) * 4) * 512 + r * 32 + qd * 8;
  int boff = ((w >> 1) * 4) * 512 + r * 32 + qd * 8;

  for (int kt = 0; kt < nIter; ++kt) {
#pragma unroll
    for (int qq = 0; qq < 2; ++qq) { gll16(ga[qq], la[qq]); gll16(gb[qq], lb[qq]); }
    ga[0] += 32; ga[1] += 32; gb[0] += 32; gb[1] += 32;
    __syncthreads();
    s16x8 af[4], bf[4];
#pragma unroll
    for (int i = 0; i < 4; ++i) af[i] = *(const s16x8*)(As + aoff + i * 512);
#pragma unroll
    for (int j = 0; j < 4; ++j) bf[j] = *(const s16x8*)(Bs + boff + j * 512);
#pragma unroll
    for (int i = 0; i < 4; ++i)
#pragma unroll
      for (int j = 0; j < 4; ++j) acc[i][j] = mfma16(af[i], bf[j], acc[i][j]);
    __syncthreads();
  }

  const float QSCALE = 0.125f * 1.44269504088896f;  // folded into q for exp2-domain attn
  int rowBase = mBlk * 128 + (w & 1) * 64;
  int colBase = nBlk * 128 + (w >> 1) * 64;
#pragma unroll
  for (int i = 0; i < 4; ++i) {
#pragma unroll
    for (int j = 0; j < 4; ++j) {
      int col = colBase + j * 16 + r;
      float bv = bias[col];
#pragma unroll
      for (int g = 0; g < 4; ++g) {
        int row = rowBase + i * 16 + qd * 4 + g;
        float v = acc[i][j][g] + bv;
        if (EPI == 0) {
          int which = col >> 10;
          int rem = col & 1023;
          int hh = rem >> 6, dd = rem & 63;
          int bb = row >> 11, tt = row & 2047;
          u16* base = (which == 0) ? q_out : (which == 1) ? k_out : v_out;
          if (which == 0) v *= QSCALE;
          base[(((size_t)(bb * 16 + hh)) * 2048 + tt) * 64 + dd] = f2bf(v);
        } else {
          outp[(size_t)row * 1024 + col] = v;
        }
      }
    }
  }
}

// ---------------- flash attention v4 ----------------
// grid (16, B*H), 256 thr. Block bx handles 64-row q-chunks (bx, 31-bx) -> 33 units.
// S^T = mfma(kf, qf): lane r owns q-row. Static-max softmax; l via ones-MFMA;
// O^T = mfma(vf, pa). Double-buffered K/V staging (prefetch kt+1 before compute),
// ONE barrier per k-tile. Per-chunk Ps buffers -> one lds_fence per k-tile.
__global__ __launch_bounds__(256) void k_attn(const u16* __restrict__ qg,
                                              const u16* __restrict__ kg,
                                              const u16* __restrict__ vtg,
                                              u16* __restrict__ yg) {
  __shared__ u16 Ks[2][64 * 64];     // [buf][row][8chunk ^ (row&7)]
  __shared__ u16 Vs[2][64 * 64];     // [buf][d]  [8chunk ^ (d&7)]
  __shared__ u16 Ps[4][2][16 * 72];  // [wave][chunk][16 q-rows][64 k], pad 72

  int bh = blockIdx.y, bb = bh >> 4, hh = bh & 15;
  int bx = blockIdx.x;
  int tid = threadIdx.x, w = tid >> 6, l = tid & 63;
  int r = l & 15, qd = l >> 4;

  int chunkA = bx, chunkB = 31 - bx;
  int nA = bx + 1, nB = 32 - bx;
  int qloc = w * 16 + r;  // q row within chunk; lane r owns this row

  // Q b-fragments (q pre-scaled by 1/8*log2e at GEMM0 epilogue)
  s16x8 qf[2][2];
#pragma unroll
  for (int i = 0; i < 2; ++i) {
    int qbase = (i == 0 ? chunkA : chunkB) * 64 + w * 16;
#pragma unroll
    for (int s = 0; s < 2; ++s)
      qf[i][s] = *(const s16x8*)(qg + ((size_t)bh * 2048 + qbase + r) * 64 + s * 32 + qd * 8);
  }

  s16x8 onesf;
#pragma unroll
  for (int e = 0; e < 8; ++e) onesf[e] = (short)0x3F80;  // bf16 1.0

  f32x4 o[2][4] = {};    // O^T: o[i][j][g] = O[q=qbase_i + r][d = 16j + 4qd + g]
  f32x4 lacc[2] = {};    // ones-MFMA row-sum

  // staging lane geometry
  int rl = l >> 3;
  int cg = (l & 7) ^ rl;
  const u16* kbase = kg + (size_t)bh * 2048 * 64;
  const u16* vbase = vtg + (size_t)bh * 64 * 2048;

  auto stage = [&](int kt, int buf) {
    int kk0 = kt * 64;
#pragma unroll
    for (int p = 0; p < 2; ++p) {
      int row = p * 32 + w * 8 + rl;
      gll16(kbase + ((size_t)(kk0 + row)) * 64 + cg * 8, Ks[buf] + p * 2048 + w * 512);
      gll16(vbase + (size_t)row * 2048 + kk0 + cg * 8, Vs[buf] + p * 2048 + w * 512);
    }
  };

  stage(0, 0);
  __syncthreads();  // vmcnt drained -> buf0 visible

  for (int kt = 0; kt < nB; ++kt) {
    int cur = kt & 1;
    if (kt + 1 < nB) stage(kt + 1, cur ^ 1);  // prefetch flies under compute

    bool doA = (kt < nA);
    f32x4 sacc[2][4] = {};
#pragma unroll
    for (int s = 0; s < 2; ++s) {
#pragma unroll
      for (int j = 0; j < 4; ++j) {
        s16x8 kf = *(const s16x8*)(Ks[cur] + (16 * j + r) * 64 + ((s * 4 + qd) ^ (r & 7)) * 8);
        if (doA) sacc[0][j] = mfma16(kf, qf[0][s], sacc[0][j]);
        sacc[1][j] = mfma16(kf, qf[1][s], sacc[1][j]);
      }
    }

    // exp2 + pack + store P for both chunks (disjoint Ps regions; WAR vs prev kt
    // covered by the loop-end barrier's lgkmcnt drain)
#pragma unroll
    for (int i = 0; i < 2; ++i) {
      if (i == 0 && !doA) continue;
      bool needMask = (kt == (i == 0 ? chunkA : chunkB));
#pragma unroll
      for (int j = 0; j < 4; ++j) {
        float p0, p1, p2, p3;  // k-local = 16j + 4qd + g
        if (needMask) {
          int kb0 = 16 * j + 4 * qd;
          p0 = (kb0 + 0 > qloc) ? 0.f : __builtin_amdgcn_exp2f(sacc[i][j][0]);
          p1 = (kb0 + 1 > qloc) ? 0.f : __builtin_amdgcn_exp2f(sacc[i][j][1]);
          p2 = (kb0 + 2 > qloc) ? 0.f : __builtin_amdgcn_exp2f(sacc[i][j][2]);
          p3 = (kb0 + 3 > qloc) ? 0.f : __builtin_amdgcn_exp2f(sacc[i][j][3]);
        } else {
          p0 = __builtin_amdgcn_exp2f(sacc[i][j][0]);
          p1 = __builtin_amdgcn_exp2f(sacc[i][j][1]);
          p2 = __builtin_amdgcn_exp2f(sacc[i][j][2]);
          p3 = __builtin_amdgcn_exp2f(sacc[i][j][3]);
        }
        uint2 pk;
        pk.x = pk_trunc(p1, p0);
        pk.y = pk_trunc(p3, p2);
        *(uint2*)(Ps[w][i] + r * 72 + j * 16 + qd * 4) = pk;  // P[q=r][k=16j+4qd..+4]
      }
    }
    lds_fence();  // P stores visible to own wave's reads

    // PV burst for both chunks (20 MFMAs back-to-back)
#pragma unroll
    for (int i = 0; i < 2; ++i) {
      if (i == 0 && !doA) continue;
#pragma unroll
      for (int s = 0; s < 2; ++s) {
        s16x8 pa = *(const s16x8*)(Ps[w][i] + r * 72 + s * 32 + qd * 8);  // P[q=r][..]
        lacc[i] = mfma16(onesf, pa, lacc[i]);
#pragma unroll
        for (int j = 0; j < 4; ++j) {
          s16x8 vf = *(const s16x8*)(Vs[cur] + (16 * j + r) * 64 + ((s * 4 + qd) ^ (r & 7)) * 8);
          o[i][j] = mfma16(vf, pa, o[i][j]);
        }
      }
    }
    __syncthreads();  // all reads of buf[cur] done + prefetch into buf[cur^1] landed
  }

  // epilogue: lane (r,qd), chunk i: y[q = qbase_i + r][d = 16j + 4qd + g], packed x4
#pragma unroll
  for (int i = 0; i < 2; ++i) {
    int qbase = (i == 0 ? chunkA : chunkB) * 64 + w * 16;
    float inv = 1.0f / lacc[i][0];
    size_t rowoff = ((size_t)bb * 2048 + qbase + r) * 1024 + hh * 64;
#pragma unroll
    for (int j = 0; j < 4; ++j) {
      u16x4 yv;
      yv[0] = f2bf(o[i][j][0] * inv);
      yv[1] = f2bf(o[i][j][1] * inv);
      yv[2] = f2bf(o[i][j][2] * inv);
      yv[3] = f2bf(o[i][j][3] * inv);
      *(u16x4*)(yg + rowoff + 16 * j + 4 * qd) = yv;
    }
  }
}

// ---------------- launch ----------------
extern "C" void kernel_launch(void* const* d_in, const int* in_sizes, int n_in,
                              void* d_out, int out_size, void* d_ws, size_t ws_size,
                              hipStream_t stream) {
  const float* x      = (const float*)d_in[0];
  const float* w_attn = (const float*)d_in[1];
  const float* b_attn = (const float*)d_in[2];
  const float* w_proj = (const float*)d_in[3];
  const float* b_proj = (const float*)d_in[4];
  float* out = (float*)d_out;

  char* ws = (char*)d_ws;
  size_t off = 0;
  auto alloc = [&](size_t bytes) -> void* {
    void* p = ws + off;
    off += (bytes + 255) & ~(size_t)255;
    return p;
  };
  const size_t BT = 8192, C = 1024;
  u16* xb  = (u16*)alloc(BT * C * 2);          // x bf16; reused as y
  u16* waT = (u16*)alloc(3072 * 1024 * 2);
  u16* wpT = (u16*)alloc(1024 * 1024 * 2);
  u16* qb  = (u16*)alloc(BT * C * 2);          // [BH][T][D], q pre-scaled
  u16* kb  = (u16*)alloc(BT * C * 2);
  u16* vb  = (u16*)alloc(BT * C * 2);
  u16* vtb = (u16*)alloc(BT * C * 2);          // [BH][D][T]
  (void)ws_size; (void)in_sizes; (void)n_in; (void)out_size;

  k_convert_x<<<4096, 256, 0, stream>>>(x, xb);
  k_transpose_w<<<dim3(96, 32), 256, 0, stream>>>(w_attn, waT, 1024, 3072);
  k_transpose_w<<<dim3(32, 32), 256, 0, stream>>>(w_proj, wpT, 1024, 1024);
  k_gemm<0><<<1536, 256, 0, stream>>>(xb, waT, b_attn, nullptr, qb, kb, vb, 1024, 32);
  k_transpose_v<<<dim3(32, 64), 256, 0, stream>>>(vb, vtb);
  k_attn<<<dim3(16, 64), 256, 0, stream>>>(qb, kb, vtb, xb /* y reuses xb */);
  k_gemm<1><<<512, 256, 0, stream>>>(xb, wpT, b_proj, out, nullptr, nullptr, nullptr, 1024, 32);
}

// Round 5
// 296.948 us; speedup vs baseline: 1.0236x; 1.0236x over previous
//
#include <hip/hip_runtime.h>
#include <math.h>

// ---------------- types / helpers ----------------
typedef short s16x8 __attribute__((ext_vector_type(8)));     // 8 bf16 in 4 VGPRs
typedef unsigned short u16;
typedef unsigned short u16x4 __attribute__((ext_vector_type(4)));
typedef float f32x4 __attribute__((ext_vector_type(4)));

__device__ __forceinline__ f32x4 mfma16(s16x8 a, s16x8 b, f32x4 c) {
  return __builtin_amdgcn_mfma_f32_16x16x32_bf16(a, b, c, 0, 0, 0);
}

// fp32 -> bf16 bits, round-to-nearest-even
__device__ __forceinline__ u16 f2bf(float f) {
  unsigned u = __builtin_bit_cast(unsigned, f);
  u = (u + 0x7fffu + ((u >> 16) & 1u)) >> 16;
  return (u16)u;
}

// pack two fp32 -> two truncated bf16 in one v_perm
__device__ __forceinline__ unsigned pk_trunc(float hi, float lo) {
  return __builtin_amdgcn_perm(__builtin_bit_cast(unsigned, hi),
                               __builtin_bit_cast(unsigned, lo), 0x07060302u);
}

// async global->LDS, 16B per lane; lds base wave-uniform, lane i lands at base + i*16
__device__ __forceinline__ void gll16(const void* g, void* l) {
  __builtin_amdgcn_global_load_lds((__attribute__((address_space(1))) void*)(void*)g,
                                   (__attribute__((address_space(3))) void*)l,
                                   16, 0, 0);
}

// wave-local LDS fence: drain DS queue + compiler ordering (no workgroup barrier)
__device__ __forceinline__ void lds_fence() {
  asm volatile("s_waitcnt lgkmcnt(0)" ::: "memory");
}

// ---------------- layout/convert kernels ----------------
__global__ __launch_bounds__(256) void k_convert_x(const float* __restrict__ x,
                                                   u16* __restrict__ xb) {
  int i = (blockIdx.x * 256 + threadIdx.x) * 8;
  const float4* xv = (const float4*)(x + i);
  float4 a = xv[0], b = xv[1];
  union { s16x8 v; u16 s[8]; } r;
  r.s[0] = f2bf(a.x); r.s[1] = f2bf(a.y); r.s[2] = f2bf(a.z); r.s[3] = f2bf(a.w);
  r.s[4] = f2bf(b.x); r.s[5] = f2bf(b.y); r.s[6] = f2bf(b.z); r.s[7] = f2bf(b.w);
  *(s16x8*)(xb + i) = r.v;
}

// in: fp32 [R][C]  ->  out: bf16 [C][R]
__global__ __launch_bounds__(256) void k_transpose_w(const float* __restrict__ in,
                                                     u16* __restrict__ out, int R, int C) {
  __shared__ float tile[32][33];
  int c0 = blockIdx.x * 32, r0 = blockIdx.y * 32;
  int tx = threadIdx.x & 31, ty = threadIdx.x >> 5;  // 32 x 8
#pragma unroll
  for (int s = 0; s < 4; ++s)
    tile[ty + 8 * s][tx] = in[(size_t)(r0 + ty + 8 * s) * C + c0 + tx];
  __syncthreads();
#pragma unroll
  for (int s = 0; s < 4; ++s)
    out[(size_t)(c0 + ty + 8 * s) * R + r0 + tx] = f2bf(tile[tx][ty + 8 * s]);
}

// v: bf16 [BH][2048][64] -> vt: bf16 [BH][64][2048]
__global__ __launch_bounds__(256) void k_transpose_v(const u16* __restrict__ v,
                                                     u16* __restrict__ vt) {
  __shared__ u16 tile[64][65];
  int bh = blockIdx.y, t0 = blockIdx.x * 64, tid = threadIdx.x;
#pragma unroll
  for (int p = 0; p < 16; ++p) {
    int idx = p * 256 + tid;
    int tt = idx >> 6, dd = idx & 63;
    tile[dd][tt] = v[((size_t)bh * 2048 + t0 + tt) * 64 + dd];
  }
  __syncthreads();
#pragma unroll
  for (int p = 0; p < 16; ++p) {
    int idx = p * 256 + tid;
    int dd = idx >> 6, tt = idx & 63;
    vt[((size_t)bh * 64 + dd) * 2048 + t0 + tt] = tile[dd][tt];
  }
}

// ---------------- GEMM: C = A[M,K] * Bt[N,K]^T + bias ----------------
// 1D grid, XCD-aware swizzle: xcd = id&7 (dispatch round-robin), each XCD owns an
// 8-mBlk strip (2 MB of A -> L2-resident) and sweeps nBlk.
template <int EPI>
__global__ __launch_bounds__(256) void k_gemm(const u16* __restrict__ A,
                                              const u16* __restrict__ Bt,
                                              const float* __restrict__ bias,
                                              float* __restrict__ outp,
                                              u16* __restrict__ q_out,
                                              u16* __restrict__ k_out,
                                              u16* __restrict__ v_out,
                                              int K, int nIter) {
  __shared__ u16 As[4096];
  __shared__ u16 Bs[4096];
  int tid = threadIdx.x, w = tid >> 6, l = tid & 63;
  int r = l & 15, qd = l >> 4;
  int id = blockIdx.x;
  int xcd = id & 7, s0 = id >> 3;
  int mBlk = xcd * 8 + (s0 & 7);
  int nBlk = s0 >> 3;
  f32x4 acc[4][4] = {};

  const u16* ga[2]; const u16* gb[2]; u16* la[2]; u16* lb[2];
#pragma unroll
  for (int qq = 0; qq < 2; ++qq) {
    int grp = 2 * w + qq;
    int rowA = mBlk * 128 + grp * 16 + (l >> 2);
    int rowB = nBlk * 128 + grp * 16 + (l >> 2);
    int kcol = (l & 3) * 8;
    ga[qq] = A + (size_t)rowA * K + kcol;
    gb[qq] = Bt + (size_t)rowB * K + kcol;
    la[qq] = As + grp * 512;
    lb[qq] = Bs + grp * 512;
  }
  int aoff = ((w & 1) * 4) * 512 + r * 32 + qd * 8;
  int boff = ((w >> 1) * 4) * 512 + r * 32 + qd * 8;

  for (int kt = 0; kt < nIter; ++kt) {
#pragma unroll
    for (int qq = 0; qq < 2; ++qq) { gll16(ga[qq], la[qq]); gll16(gb[qq], lb[qq]); }
    ga[0] += 32; ga[1] += 32; gb[0] += 32; gb[1] += 32;
    __syncthreads();
    s16x8 af[4], bf[4];
#pragma unroll
    for (int i = 0; i < 4; ++i) af[i] = *(const s16x8*)(As + aoff + i * 512);
#pragma unroll
    for (int j = 0; j < 4; ++j) bf[j] = *(const s16x8*)(Bs + boff + j * 512);
#pragma unroll
    for (int i = 0; i < 4; ++i)
#pragma unroll
      for (int j = 0; j < 4; ++j) acc[i][j] = mfma16(af[i], bf[j], acc[i][j]);
    __syncthreads();
  }

  const float QSCALE = 0.125f * 1.44269504088896f;  // folded into q for exp2-domain attn
  int rowBase = mBlk * 128 + (w & 1) * 64;
  int colBase = nBlk * 128 + (w >> 1) * 64;
#pragma unroll
  for (int i = 0; i < 4; ++i) {
#pragma unroll
    for (int j = 0; j < 4; ++j) {
      int col = colBase + j * 16 + r;
      float bv = bias[col];
#pragma unroll
      for (int g = 0; g < 4; ++g) {
        int row = rowBase + i * 16 + qd * 4 + g;
        float v = acc[i][j][g] + bv;
        if (EPI == 0) {
          int which = col >> 10;
          int rem = col & 1023;
          int hh = rem >> 6, dd = rem & 63;
          int bb = row >> 11, tt = row & 2047;
          u16* base = (which == 0) ? q_out : (which == 1) ? k_out : v_out;
          if (which == 0) v *= QSCALE;
          base[(((size_t)(bb * 16 + hh)) * 2048 + tt) * 64 + dd] = f2bf(v);
        } else {
          outp[(size_t)row * 1024 + col] = v;
        }
      }
    }
  }
}

// ---------------- flash attention v5 ----------------
// grid (16, B*H), 256 thr. Block bx handles 64-row q-chunks (bx, 31-bx) -> 33 units.
// S^T = mfma(kf, qf): lane r owns q-row. Static-max softmax; l via ones-MFMA;
// O^T = mfma(vf, pa). Double-buffered K/V staging, ONE barrier per k-tile.
// LDS = 16K(Ks dbuf) + 16K(Vs dbuf) + 8K(Ps) = 40960 B exactly -> 4 blocks/CU.
// Ps is one 16x64 tile/wave, XOR-swizzled (col ^= (r&7)*8) instead of padded;
// chunk B reuses it behind wave-local lgkm fences.
__global__ __launch_bounds__(256) void k_attn(const u16* __restrict__ qg,
                                              const u16* __restrict__ kg,
                                              const u16* __restrict__ vtg,
                                              u16* __restrict__ yg) {
  __shared__ u16 Ks[2][64 * 64];   // [buf][row][8chunk ^ (row&7)]
  __shared__ u16 Vs[2][64 * 64];   // [buf][d]  [8chunk ^ (d&7)]
  __shared__ u16 Ps[4][16 * 64];   // [wave][q-row r][col ^ ((r&7)*8)]

  int bh = blockIdx.y, bb = bh >> 4, hh = bh & 15;
  int bx = blockIdx.x;
  int tid = threadIdx.x, w = tid >> 6, l = tid & 63;
  int r = l & 15, qd = l >> 4;
  int psw = (r & 7) * 8;  // Ps column swizzle key for this lane's q-row

  int chunkA = bx, chunkB = 31 - bx;
  int nA = bx + 1, nB = 32 - bx;
  int qloc = w * 16 + r;  // q row within chunk; lane r owns this row

  // Q b-fragments (q pre-scaled by 1/8*log2e at GEMM0 epilogue)
  s16x8 qf[2][2];
#pragma unroll
  for (int i = 0; i < 2; ++i) {
    int qbase = (i == 0 ? chunkA : chunkB) * 64 + w * 16;
#pragma unroll
    for (int s = 0; s < 2; ++s)
      qf[i][s] = *(const s16x8*)(qg + ((size_t)bh * 2048 + qbase + r) * 64 + s * 32 + qd * 8);
  }

  s16x8 onesf;
#pragma unroll
  for (int e = 0; e < 8; ++e) onesf[e] = (short)0x3F80;  // bf16 1.0

  f32x4 o[2][4] = {};    // O^T: o[i][j][g] = O[q=qbase_i + r][d = 16j + 4qd + g]
  f32x4 lacc[2] = {};    // ones-MFMA row-sum

  // staging lane geometry
  int rl = l >> 3;
  int cg = (l & 7) ^ rl;
  const u16* kbase = kg + (size_t)bh * 2048 * 64;
  const u16* vbase = vtg + (size_t)bh * 64 * 2048;

  auto stage = [&](int kt, int buf) {
    int kk0 = kt * 64;
#pragma unroll
    for (int p = 0; p < 2; ++p) {
      int row = p * 32 + w * 8 + rl;
      gll16(kbase + ((size_t)(kk0 + row)) * 64 + cg * 8, Ks[buf] + p * 2048 + w * 512);
      gll16(vbase + (size_t)row * 2048 + kk0 + cg * 8, Vs[buf] + p * 2048 + w * 512);
    }
  };

  stage(0, 0);
  __syncthreads();  // vmcnt drained -> buf0 visible

  for (int kt = 0; kt < nB; ++kt) {
    int cur = kt & 1;
    if (kt + 1 < nB) stage(kt + 1, cur ^ 1);  // prefetch flies under compute

    bool doA = (kt < nA);
    f32x4 sacc[2][4] = {};
#pragma unroll
    for (int s = 0; s < 2; ++s) {
#pragma unroll
      for (int j = 0; j < 4; ++j) {
        s16x8 kf = *(const s16x8*)(Ks[cur] + (16 * j + r) * 64 + ((s * 4 + qd) ^ (r & 7)) * 8);
        if (doA) sacc[0][j] = mfma16(kf, qf[0][s], sacc[0][j]);
        sacc[1][j] = mfma16(kf, qf[1][s], sacc[1][j]);
      }
    }

#pragma unroll
    for (int i = 0; i < 2; ++i) {
      if (i == 0 && !doA) continue;
      bool needMask = (kt == (i == 0 ? chunkA : chunkB));
      if (i == 1) lds_fence();  // WAR: chunk A's PV reads of Ps[w] done before overwrite
                                // (i==0's WAR vs prev iter is covered by loop-end barrier)
#pragma unroll
      for (int j = 0; j < 4; ++j) {
        float p0, p1, p2, p3;  // k-local = 16j + 4qd + g
        if (needMask) {
          int kb0 = 16 * j + 4 * qd;
          p0 = (kb0 + 0 > qloc) ? 0.f : __builtin_amdgcn_exp2f(sacc[i][j][0]);
          p1 = (kb0 + 1 > qloc) ? 0.f : __builtin_amdgcn_exp2f(sacc[i][j][1]);
          p2 = (kb0 + 2 > qloc) ? 0.f : __builtin_amdgcn_exp2f(sacc[i][j][2]);
          p3 = (kb0 + 3 > qloc) ? 0.f : __builtin_amdgcn_exp2f(sacc[i][j][3]);
        } else {
          p0 = __builtin_amdgcn_exp2f(sacc[i][j][0]);
          p1 = __builtin_amdgcn_exp2f(sacc[i][j][1]);
          p2 = __builtin_amdgcn_exp2f(sacc[i][j][2]);
          p3 = __builtin_amdgcn_exp2f(sacc[i][j][3]);
        }
        uint2 pk;
        pk.x = pk_trunc(p1, p0);
        pk.y = pk_trunc(p3, p2);
        // P[q=r][k=16j+4qd..+4], column XOR-swizzled by (r&7)*8
        *(uint2*)(Ps[w] + r * 64 + ((j * 16 + qd * 4) ^ psw)) = pk;
      }
      lds_fence();  // P stores visible to own wave's reads

#pragma unroll
      for (int s = 0; s < 2; ++s) {
        s16x8 pa = *(const s16x8*)(Ps[w] + r * 64 + ((s * 32 + qd * 8) ^ psw));  // P[q=r][..]
        lacc[i] = mfma16(onesf, pa, lacc[i]);
#pragma unroll
        for (int j = 0; j < 4; ++j) {
          s16x8 vf = *(const s16x8*)(Vs[cur] + (16 * j + r) * 64 + ((s * 4 + qd) ^ (r & 7)) * 8);
          o[i][j] = mfma16(vf, pa, o[i][j]);
        }
      }
    }
    __syncthreads();  // all reads of buf[cur] done + prefetch into buf[cur^1] landed
  }

  // epilogue: lane (r,qd), chunk i: y[q = qbase_i + r][d = 16j + 4qd + g], packed x4
#pragma unroll
  for (int i = 0; i < 2; ++i) {
    int qbase = (i == 0 ? chunkA : chunkB) * 64 + w * 16;
    float inv = 1.0f / lacc[i][0];
    size_t rowoff = ((size_t)bb * 2048 + qbase + r) * 1024 + hh * 64;
#pragma unroll
    for (int j = 0; j < 4; ++j) {
      u16x4 yv;
      yv[0] = f2bf(o[i][j][0] * inv);
      yv[1] = f2bf(o[i][j][1] * inv);
      yv[2] = f2bf(o[i][j][2] * inv);
      yv[3] = f2bf(o[i][j][3] * inv);
      *(u16x4*)(yg + rowoff + 16 * j + 4 * qd) = yv;
    }
  }
}

// ---------------- launch ----------------
extern "C" void kernel_launch(void* const* d_in, const int* in_sizes, int n_in,
                              void* d_out, int out_size, void* d_ws, size_t ws_size,
                              hipStream_t stream) {
  const float* x      = (const float*)d_in[0];
  const float* w_attn = (const float*)d_in[1];
  const float* b_attn = (const float*)d_in[2];
  const float* w_proj = (const float*)d_in[3];
  const float* b_proj = (const float*)d_in[4];
  float* out = (float*)d_out;

  char* ws = (char*)d_ws;
  size_t off = 0;
  auto alloc = [&](size_t bytes) -> void* {
    void* p = ws + off;
    off += (bytes + 255) & ~(size_t)255;
    return p;
  };
  const size_t BT = 8192, C = 1024;
  u16* xb  = (u16*)alloc(BT * C * 2);          // x bf16; reused as y
  u16* waT = (u16*)alloc(3072 * 1024 * 2);
  u16* wpT = (u16*)alloc(1024 * 1024 * 2);
  u16* qb  = (u16*)alloc(BT * C * 2);          // [BH][T][D], q pre-scaled
  u16* kb  = (u16*)alloc(BT * C * 2);
  u16* vb  = (u16*)alloc(BT * C * 2);
  u16* vtb = (u16*)alloc(BT * C * 2);          // [BH][D][T]
  (void)ws_size; (void)in_sizes; (void)n_in; (void)out_size;

  k_convert_x<<<4096, 256, 0, stream>>>(x, xb);
  k_transpose_w<<<dim3(96, 32), 256, 0, stream>>>(w_attn, waT, 1024, 3072);
  k_transpose_w<<<dim3(32, 32), 256, 0, stream>>>(w_proj, wpT, 1024, 1024);
  k_gemm<0><<<1536, 256, 0, stream>>>(xb, waT, b_attn, nullptr, qb, kb, vb, 1024, 32);
  k_transpose_v<<<dim3(32, 64), 256, 0, stream>>>(vb, vtb);
  k_attn<<<dim3(16, 64), 256, 0, stream>>>(qb, kb, vtb, xb /* y reuses xb */);
  k_gemm<1><<<512, 256, 0, stream>>>(xb, wpT, b_proj, out, nullptr, nullptr, nullptr, 1024, 32);
}

// Round 6
// 277.854 us; speedup vs baseline: 1.0939x; 1.0687x over previous
//
#include <hip/hip_runtime.h>
#include <math.h>

// ---------------- types / helpers ----------------
typedef short s16x8 __attribute__((ext_vector_type(8)));     // 8 bf16 in 4 VGPRs
typedef unsigned short u16;
typedef unsigned short u16x4 __attribute__((ext_vector_type(4)));
typedef float f32x4 __attribute__((ext_vector_type(4)));

__device__ __forceinline__ f32x4 mfma16(s16x8 a, s16x8 b, f32x4 c) {
  return __builtin_amdgcn_mfma_f32_16x16x32_bf16(a, b, c, 0, 0, 0);
}

// fp32 -> bf16 bits, round-to-nearest-even
__device__ __forceinline__ u16 f2bf(float f) {
  unsigned u = __builtin_bit_cast(unsigned, f);
  u = (u + 0x7fffu + ((u >> 16) & 1u)) >> 16;
  return (u16)u;
}

// pack two fp32 -> two truncated bf16 in one v_perm
__device__ __forceinline__ unsigned pk_trunc(float hi, float lo) {
  return __builtin_amdgcn_perm(__builtin_bit_cast(unsigned, hi),
                               __builtin_bit_cast(unsigned, lo), 0x07060302u);
}

// async global->LDS, 16B per lane; lds base wave-uniform, lane i lands at base + i*16
__device__ __forceinline__ void gll16(const void* g, void* l) {
  __builtin_amdgcn_global_load_lds((__attribute__((address_space(1))) void*)(void*)g,
                                   (__attribute__((address_space(3))) void*)l,
                                   16, 0, 0);
}

// wave-local LDS fence: drain DS queue + compiler ordering (no workgroup barrier)
__device__ __forceinline__ void lds_fence() {
  asm volatile("s_waitcnt lgkmcnt(0)" ::: "memory");
}

// ---------------- layout/convert kernels ----------------
__global__ __launch_bounds__(256) void k_convert_x(const float* __restrict__ x,
                                                   u16* __restrict__ xb) {
  int i = (blockIdx.x * 256 + threadIdx.x) * 8;
  const float4* xv = (const float4*)(x + i);
  float4 a = xv[0], b = xv[1];
  union { s16x8 v; u16 s[8]; } r;
  r.s[0] = f2bf(a.x); r.s[1] = f2bf(a.y); r.s[2] = f2bf(a.z); r.s[3] = f2bf(a.w);
  r.s[4] = f2bf(b.x); r.s[5] = f2bf(b.y); r.s[6] = f2bf(b.z); r.s[7] = f2bf(b.w);
  *(s16x8*)(xb + i) = r.v;
}

// in: fp32 [R][C]  ->  out: bf16 [C][R]
__global__ __launch_bounds__(256) void k_transpose_w(const float* __restrict__ in,
                                                     u16* __restrict__ out, int R, int C) {
  __shared__ float tile[32][33];
  int c0 = blockIdx.x * 32, r0 = blockIdx.y * 32;
  int tx = threadIdx.x & 31, ty = threadIdx.x >> 5;  // 32 x 8
#pragma unroll
  for (int s = 0; s < 4; ++s)
    tile[ty + 8 * s][tx] = in[(size_t)(r0 + ty + 8 * s) * C + c0 + tx];
  __syncthreads();
#pragma unroll
  for (int s = 0; s < 4; ++s)
    out[(size_t)(c0 + ty + 8 * s) * R + r0 + tx] = f2bf(tile[tx][ty + 8 * s]);
}

// ---------------- GEMM: C = A[M,K] * Bt[N,K]^T + bias ----------------
// 1D grid, XCD-aware swizzle. EPI 0: scatter q (scaled), k as [BH][T][D]; v directly
// transposed to [BH][D][T] (g-consecutive rows -> vectorized u16x4 store).
template <int EPI>
__global__ __launch_bounds__(256) void k_gemm(const u16* __restrict__ A,
                                              const u16* __restrict__ Bt,
                                              const float* __restrict__ bias,
                                              float* __restrict__ outp,
                                              u16* __restrict__ q_out,
                                              u16* __restrict__ k_out,
                                              u16* __restrict__ vt_out,
                                              int K, int nIter) {
  __shared__ u16 As[4096];
  __shared__ u16 Bs[4096];
  int tid = threadIdx.x, w = tid >> 6, l = tid & 63;
  int r = l & 15, qd = l >> 4;
  int id = blockIdx.x;
  int xcd = id & 7, s0 = id >> 3;
  int mBlk = xcd * 8 + (s0 & 7);
  int nBlk = s0 >> 3;
  f32x4 acc[4][4] = {};

  const u16* ga[2]; const u16* gb[2]; u16* la[2]; u16* lb[2];
#pragma unroll
  for (int qq = 0; qq < 2; ++qq) {
    int grp = 2 * w + qq;
    int rowA = mBlk * 128 + grp * 16 + (l >> 2);
    int rowB = nBlk * 128 + grp * 16 + (l >> 2);
    int kcol = (l & 3) * 8;
    ga[qq] = A + (size_t)rowA * K + kcol;
    gb[qq] = Bt + (size_t)rowB * K + kcol;
    la[qq] = As + grp * 512;
    lb[qq] = Bs + grp * 512;
  }
  int aoff = ((w & 1) * 4) * 512 + r * 32 + qd * 8;
  int boff = ((w >> 1) * 4) * 512 + r * 32 + qd * 8;

  for (int kt = 0; kt < nIter; ++kt) {
#pragma unroll
    for (int qq = 0; qq < 2; ++qq) { gll16(ga[qq], la[qq]); gll16(gb[qq], lb[qq]); }
    ga[0] += 32; ga[1] += 32; gb[0] += 32; gb[1] += 32;
    __syncthreads();
    s16x8 af[4], bf[4];
#pragma unroll
    for (int i = 0; i < 4; ++i) af[i] = *(const s16x8*)(As + aoff + i * 512);
#pragma unroll
    for (int j = 0; j < 4; ++j) bf[j] = *(const s16x8*)(Bs + boff + j * 512);
#pragma unroll
    for (int i = 0; i < 4; ++i)
#pragma unroll
      for (int j = 0; j < 4; ++j) acc[i][j] = mfma16(af[i], bf[j], acc[i][j]);
    __syncthreads();
  }

  const float QSCALE = 0.125f * 1.44269504088896f;  // folded into q for exp2-domain attn
  int rowBase = mBlk * 128 + (w & 1) * 64;
  int colBase = nBlk * 128 + (w >> 1) * 64;
#pragma unroll
  for (int i = 0; i < 4; ++i) {
#pragma unroll
    for (int j = 0; j < 4; ++j) {
      int col = colBase + j * 16 + r;
      float bv = bias[col];
      float vv[4];
#pragma unroll
      for (int g = 0; g < 4; ++g) vv[g] = acc[i][j][g] + bv;
      int row0 = rowBase + i * 16 + qd * 4;  // rows row0..row0+3 (same 2048-block)
      if (EPI == 0) {
        int which = col >> 10;
        int rem = col & 1023;
        int hh = rem >> 6, dd = rem & 63;
        int bb = row0 >> 11, tt0 = row0 & 2047;
        if (which == 2) {
          // v -> [BH][D][T], 4 consecutive t: one 8B store
          u16x4 pk;
#pragma unroll
          for (int g = 0; g < 4; ++g) pk[g] = f2bf(vv[g]);
          *(u16x4*)(vt_out + (((size_t)(bb * 16 + hh)) * 64 + dd) * 2048 + tt0) = pk;
        } else {
          u16* base = (which == 0) ? q_out : k_out;
#pragma unroll
          for (int g = 0; g < 4; ++g) {
            float v = vv[g];
            if (which == 0) v *= QSCALE;
            base[(((size_t)(bb * 16 + hh)) * 2048 + tt0 + g) * 64 + dd] = f2bf(v);
          }
        }
      } else {
#pragma unroll
        for (int g = 0; g < 4; ++g)
          outp[(size_t)(row0 + g) * 1024 + col] = vv[g];
      }
    }
  }
}

// ---------------- flash attention v6 ----------------
// grid (8, B*H), 256 thr. Block bx handles FOUR 64-row q-chunks {bx,15-bx,16+bx,31-bx}
// (Sum n = 66, balanced). Wave w owns rows [16w,16w+16) of EACH chunk -> 64 q-rows/wave:
// the 8 kf + 8 vf LDS reads per tile are amortized over 64 q-rows (2x less LDS traffic
// per q-row than v5 -- kernel is LDS-throughput-bound). S^T=mfma(kf,qf), static-max
// softmax, l via ones-MFMA, O^T=mfma(vf,pa). Dbuf K/V staging, 1 barrier + 1 fence/tile.
// LDS = 16K + 16K + 32K(Ps: 4 waves x 64 rows x 64) = 64 KiB -> 2 blocks/CU.
__global__ __launch_bounds__(256, 2) void k_attn(const u16* __restrict__ qg,
                                                 const u16* __restrict__ kg,
                                                 const u16* __restrict__ vtg,
                                                 u16* __restrict__ yg) {
  __shared__ u16 Ks[2][64 * 64];   // [buf][row][8chunk ^ (row&7)]
  __shared__ u16 Vs[2][64 * 64];   // [buf][d]  [8chunk ^ (d&7)]
  __shared__ u16 Ps[4][64 * 64];   // [wave][c*16 + r][col ^ ((r&7)*8)]

  int bh = blockIdx.y, bb = bh >> 4, hh = bh & 15;
  int bx = blockIdx.x;  // 0..7
  int tid = threadIdx.x, w = tid >> 6, l = tid & 63;
  int r = l & 15, qd = l >> 4;
  int psw = (r & 7) * 8;

  const int chunk[4] = {bx, 15 - bx, 16 + bx, 31 - bx};
  const int nend[4]  = {bx + 1, 16 - bx, 17 + bx, 32 - bx};
  int nmax = 32 - bx;
  int qloc = w * 16 + r;  // within-chunk q row owned by lane r

  // Q b-fragments (q pre-scaled by 1/8*log2e at GEMM0 epilogue)
  s16x8 qf[4][2];
#pragma unroll
  for (int c = 0; c < 4; ++c) {
    int qbase = chunk[c] * 64 + w * 16;
#pragma unroll
    for (int s = 0; s < 2; ++s)
      qf[c][s] = *(const s16x8*)(qg + ((size_t)bh * 2048 + qbase + r) * 64 + s * 32 + qd * 8);
  }

  s16x8 onesf;
#pragma unroll
  for (int e = 0; e < 8; ++e) onesf[e] = (short)0x3F80;  // bf16 1.0

  f32x4 o[4][4] = {};    // O^T: o[c][j][g] = O[q=qbase_c + r][d = 16j + 4qd + g]
  f32x4 lacc[4] = {};    // ones-MFMA row-sum

  // staging lane geometry
  int rl = l >> 3;
  int cg = (l & 7) ^ rl;
  const u16* kbase = kg + (size_t)bh * 2048 * 64;
  const u16* vbase = vtg + (size_t)bh * 64 * 2048;

  auto stage = [&](int kt, int buf) {
    int kk0 = kt * 64;
#pragma unroll
    for (int p = 0; p < 2; ++p) {
      int row = p * 32 + w * 8 + rl;
      gll16(kbase + ((size_t)(kk0 + row)) * 64 + cg * 8, Ks[buf] + p * 2048 + w * 512);
      gll16(vbase + (size_t)row * 2048 + kk0 + cg * 8, Vs[buf] + p * 2048 + w * 512);
    }
  };

  stage(0, 0);
  __syncthreads();  // vmcnt drained -> buf0 visible

  for (int kt = 0; kt < nmax; ++kt) {
    int cur = kt & 1;
    if (kt + 1 < nmax) stage(kt + 1, cur ^ 1);  // prefetch flies under compute

    // ---- QK^T for all active chunks; kf read once, feeds up to 4 chunks ----
    f32x4 sacc[4][4];
#pragma unroll
    for (int c = 0; c < 4; ++c)
      if (kt < nend[c])
#pragma unroll
        for (int j = 0; j < 4; ++j) sacc[c][j] = f32x4{0.f, 0.f, 0.f, 0.f};
#pragma unroll
    for (int s = 0; s < 2; ++s) {
#pragma unroll
      for (int j = 0; j < 4; ++j) {
        s16x8 kf = *(const s16x8*)(Ks[cur] + (16 * j + r) * 64 + ((s * 4 + qd) ^ (r & 7)) * 8);
#pragma unroll
        for (int c = 0; c < 4; ++c)
          if (kt < nend[c]) sacc[c][j] = mfma16(kf, qf[c][s], sacc[c][j]);
      }
    }

    // ---- softmax + P store (chunk-private Ps rows -> no WAR fence needed) ----
#pragma unroll
    for (int c = 0; c < 4; ++c) {
      if (kt >= nend[c]) continue;
      bool needMask = (kt == chunk[c]);  // diagonal tile
#pragma unroll
      for (int j = 0; j < 4; ++j) {
        float p0, p1, p2, p3;  // k-local = 16j + 4qd + g
        if (needMask) {
          int kb0 = 16 * j + 4 * qd;
          p0 = (kb0 + 0 > qloc) ? 0.f : __builtin_amdgcn_exp2f(sacc[c][j][0]);
          p1 = (kb0 + 1 > qloc) ? 0.f : __builtin_amdgcn_exp2f(sacc[c][j][1]);
          p2 = (kb0 + 2 > qloc) ? 0.f : __builtin_amdgcn_exp2f(sacc[c][j][2]);
          p3 = (kb0 + 3 > qloc) ? 0.f : __builtin_amdgcn_exp2f(sacc[c][j][3]);
        } else {
          p0 = __builtin_amdgcn_exp2f(sacc[c][j][0]);
          p1 = __builtin_amdgcn_exp2f(sacc[c][j][1]);
          p2 = __builtin_amdgcn_exp2f(sacc[c][j][2]);
          p3 = __builtin_amdgcn_exp2f(sacc[c][j][3]);
        }
        uint2 pk;
        pk.x = pk_trunc(p1, p0);
        pk.y = pk_trunc(p3, p2);
        *(uint2*)(Ps[w] + (c * 16 + r) * 64 + ((j * 16 + qd * 4) ^ psw)) = pk;
      }
    }
    lds_fence();  // P stores visible to own wave's reads

    // ---- PV burst: vf read once per (s,j), shared by all active chunks ----
#pragma unroll
    for (int s = 0; s < 2; ++s) {
      s16x8 pa[4];
#pragma unroll
      for (int c = 0; c < 4; ++c)
        if (kt < nend[c]) {
          pa[c] = *(const s16x8*)(Ps[w] + (c * 16 + r) * 64 + ((s * 32 + qd * 8) ^ psw));
          lacc[c] = mfma16(onesf, pa[c], lacc[c]);
        }
#pragma unroll
      for (int j = 0; j < 4; ++j) {
        s16x8 vf = *(const s16x8*)(Vs[cur] + (16 * j + r) * 64 + ((s * 4 + qd) ^ (r & 7)) * 8);
#pragma unroll
        for (int c = 0; c < 4; ++c)
          if (kt < nend[c]) o[c][j] = mfma16(vf, pa[c], o[c][j]);
      }
    }
    __syncthreads();  // all reads of buf[cur] done + prefetch into buf[cur^1] landed
  }

  // epilogue: lane (r,qd), chunk c: y[q = qbase_c + r][d = 16j + 4qd + g], packed x4
#pragma unroll
  for (int c = 0; c < 4; ++c) {
    int qbase = chunk[c] * 64 + w * 16;
    float inv = 1.0f / lacc[c][0];
    size_t rowoff = ((size_t)bb * 2048 + qbase + r) * 1024 + hh * 64;
#pragma unroll
    for (int j = 0; j < 4; ++j) {
      u16x4 yv;
      yv[0] = f2bf(o[c][j][0] * inv);
      yv[1] = f2bf(o[c][j][1] * inv);
      yv[2] = f2bf(o[c][j][2] * inv);
      yv[3] = f2bf(o[c][j][3] * inv);
      *(u16x4*)(yg + rowoff + 16 * j + 4 * qd) = yv;
    }
  }
}

// ---------------- launch ----------------
extern "C" void kernel_launch(void* const* d_in, const int* in_sizes, int n_in,
                              void* d_out, int out_size, void* d_ws, size_t ws_size,
                              hipStream_t stream) {
  const float* x      = (const float*)d_in[0];
  const float* w_attn = (const float*)d_in[1];
  const float* b_attn = (const float*)d_in[2];
  const float* w_proj = (const float*)d_in[3];
  const float* b_proj = (const float*)d_in[4];
  float* out = (float*)d_out;

  char* ws = (char*)d_ws;
  size_t off = 0;
  auto alloc = [&](size_t bytes) -> void* {
    void* p = ws + off;
    off += (bytes + 255) & ~(size_t)255;
    return p;
  };
  const size_t BT = 8192, C = 1024;
  u16* xb  = (u16*)alloc(BT * C * 2);          // x bf16; reused as y
  u16* waT = (u16*)alloc(3072 * 1024 * 2);
  u16* wpT = (u16*)alloc(1024 * 1024 * 2);
  u16* qb  = (u16*)alloc(BT * C * 2);          // [BH][T][D], q pre-scaled
  u16* kb  = (u16*)alloc(BT * C * 2);          // [BH][T][D]
  u16* vtb = (u16*)alloc(BT * C * 2);          // [BH][D][T] (written by GEMM0 directly)
  (void)ws_size; (void)in_sizes; (void)n_in; (void)out_size;

  k_convert_x<<<4096, 256, 0, stream>>>(x, xb);
  k_transpose_w<<<dim3(96, 32), 256, 0, stream>>>(w_attn, waT, 1024, 3072);
  k_transpose_w<<<dim3(32, 32), 256, 0, stream>>>(w_proj, wpT, 1024, 1024);
  k_gemm<0><<<1536, 256, 0, stream>>>(xb, waT, b_attn, nullptr, qb, kb, vtb, 1024, 32);
  k_attn<<<dim3(8, 64), 256, 0, stream>>>(qb, kb, vtb, xb /* y reuses xb */);
  k_gemm<1><<<512, 256, 0, stream>>>(xb, wpT, b_proj, out, nullptr, nullptr, nullptr, 1024, 32);
}

// Round 7
// 267.045 us; speedup vs baseline: 1.1382x; 1.0405x over previous
//
#include <hip/hip_runtime.h>
#include <math.h>

// ---------------- types / helpers ----------------
typedef short s16x8 __attribute__((ext_vector_type(8)));     // 8 bf16 in 4 VGPRs
typedef unsigned short u16;
typedef unsigned short u16x4 __attribute__((ext_vector_type(4)));
typedef float f32x4 __attribute__((ext_vector_type(4)));

__device__ __forceinline__ f32x4 mfma16(s16x8 a, s16x8 b, f32x4 c) {
  return __builtin_amdgcn_mfma_f32_16x16x32_bf16(a, b, c, 0, 0, 0);
}

// fp32 -> bf16 bits, round-to-nearest-even
__device__ __forceinline__ u16 f2bf(float f) {
  unsigned u = __builtin_bit_cast(unsigned, f);
  u = (u + 0x7fffu + ((u >> 16) & 1u)) >> 16;
  return (u16)u;
}

// pack two fp32 -> two truncated bf16 in one v_perm
__device__ __forceinline__ unsigned pk_trunc(float hi, float lo) {
  return __builtin_amdgcn_perm(__builtin_bit_cast(unsigned, hi),
                               __builtin_bit_cast(unsigned, lo), 0x07060302u);
}

// async global->LDS, 16B per lane; lds base wave-uniform, lane i lands at base + i*16
__device__ __forceinline__ void gll16(const void* g, void* l) {
  __builtin_amdgcn_global_load_lds((__attribute__((address_space(1))) void*)(void*)g,
                                   (__attribute__((address_space(3))) void*)l,
                                   16, 0, 0);
}

// wave-local LDS fence: drain DS queue + compiler ordering (no workgroup barrier)
__device__ __forceinline__ void lds_fence() {
  asm volatile("s_waitcnt lgkmcnt(0)" ::: "memory");
}

// ---------------- layout/convert kernels ----------------
__global__ __launch_bounds__(256) void k_convert_x(const float* __restrict__ x,
                                                   u16* __restrict__ xb) {
  int i = (blockIdx.x * 256 + threadIdx.x) * 8;
  const float4* xv = (const float4*)(x + i);
  float4 a = xv[0], b = xv[1];
  union { s16x8 v; u16 s[8]; } r;
  r.s[0] = f2bf(a.x); r.s[1] = f2bf(a.y); r.s[2] = f2bf(a.z); r.s[3] = f2bf(a.w);
  r.s[4] = f2bf(b.x); r.s[5] = f2bf(b.y); r.s[6] = f2bf(b.z); r.s[7] = f2bf(b.w);
  *(s16x8*)(xb + i) = r.v;
}

// in: fp32 [R][C]  ->  out: bf16 [C][R]
__global__ __launch_bounds__(256) void k_transpose_w(const float* __restrict__ in,
                                                     u16* __restrict__ out, int R, int C) {
  __shared__ float tile[32][33];
  int c0 = blockIdx.x * 32, r0 = blockIdx.y * 32;
  int tx = threadIdx.x & 31, ty = threadIdx.x >> 5;  // 32 x 8
#pragma unroll
  for (int s = 0; s < 4; ++s)
    tile[ty + 8 * s][tx] = in[(size_t)(r0 + ty + 8 * s) * C + c0 + tx];
  __syncthreads();
#pragma unroll
  for (int s = 0; s < 4; ++s)
    out[(size_t)(c0 + ty + 8 * s) * R + r0 + tx] = f2bf(tile[tx][ty + 8 * s]);
}

// ---------------- GEMM: C = A[M,K] * Bt[N,K]^T + bias ----------------
// 1D grid, XCD-aware swizzle. Double-buffered LDS staging: prefetch tile kt+1
// (global_load_lds width=16) before computing on tile kt -> the barrier drain at
// loop end no longer exposes the full L2 latency. LDS 32KB; VGPR (~164) caps
// occupancy at 3 blocks/CU, so the dbuf costs no occupancy.
// EPI 0: scatter q (scaled), k as [BH][T][D]; v transposed to [BH][D][T].
template <int EPI>
__global__ __launch_bounds__(256) void k_gemm(const u16* __restrict__ A,
                                              const u16* __restrict__ Bt,
                                              const float* __restrict__ bias,
                                              float* __restrict__ outp,
                                              u16* __restrict__ q_out,
                                              u16* __restrict__ k_out,
                                              u16* __restrict__ vt_out,
                                              int K, int nIter) {
  __shared__ u16 As[2][4096];
  __shared__ u16 Bs[2][4096];
  int tid = threadIdx.x, w = tid >> 6, l = tid & 63;
  int r = l & 15, qd = l >> 4;
  int id = blockIdx.x;
  int xcd = id & 7, s0 = id >> 3;
  int mBlk = xcd * 8 + (s0 & 7);
  int nBlk = s0 >> 3;
  f32x4 acc[4][4] = {};

  const u16* ga[2]; const u16* gb[2]; int lgrp[2];
#pragma unroll
  for (int qq = 0; qq < 2; ++qq) {
    int grp = 2 * w + qq;
    int rowA = mBlk * 128 + grp * 16 + (l >> 2);
    int rowB = nBlk * 128 + grp * 16 + (l >> 2);
    int kcol = (l & 3) * 8;
    ga[qq] = A + (size_t)rowA * K + kcol;
    gb[qq] = Bt + (size_t)rowB * K + kcol;
    lgrp[qq] = grp * 512;
  }
  int aoff = ((w & 1) * 4) * 512 + r * 32 + qd * 8;
  int boff = ((w >> 1) * 4) * 512 + r * 32 + qd * 8;

  auto stageg = [&](int kt, int buf) {
#pragma unroll
    for (int qq = 0; qq < 2; ++qq) {
      gll16(ga[qq] + kt * 32, As[buf] + lgrp[qq]);
      gll16(gb[qq] + kt * 32, Bs[buf] + lgrp[qq]);
    }
  };

  stageg(0, 0);
  __syncthreads();  // buf0 visible

  for (int kt = 0; kt < nIter; ++kt) {
    int cur = kt & 1;
    if (kt + 1 < nIter) stageg(kt + 1, cur ^ 1);  // prefetch flies under compute
    s16x8 af[4], bf[4];
#pragma unroll
    for (int i = 0; i < 4; ++i) af[i] = *(const s16x8*)(As[cur] + aoff + i * 512);
#pragma unroll
    for (int j = 0; j < 4; ++j) bf[j] = *(const s16x8*)(Bs[cur] + boff + j * 512);
#pragma unroll
    for (int i = 0; i < 4; ++i)
#pragma unroll
      for (int j = 0; j < 4; ++j) acc[i][j] = mfma16(af[i], bf[j], acc[i][j]);
    __syncthreads();  // reads of cur done + prefetch into cur^1 landed
  }

  const float QSCALE = 0.125f * 1.44269504088896f;  // folded into q for exp2-domain attn
  int rowBase = mBlk * 128 + (w & 1) * 64;
  int colBase = nBlk * 128 + (w >> 1) * 64;
#pragma unroll
  for (int i = 0; i < 4; ++i) {
#pragma unroll
    for (int j = 0; j < 4; ++j) {
      int col = colBase + j * 16 + r;
      float bv = bias[col];
      float vv[4];
#pragma unroll
      for (int g = 0; g < 4; ++g) vv[g] = acc[i][j][g] + bv;
      int row0 = rowBase + i * 16 + qd * 4;  // rows row0..row0+3 (same 2048-block)
      if (EPI == 0) {
        int which = col >> 10;
        int rem = col & 1023;
        int hh = rem >> 6, dd = rem & 63;
        int bb = row0 >> 11, tt0 = row0 & 2047;
        if (which == 2) {
          // v -> [BH][D][T], 4 consecutive t: one 8B store
          u16x4 pk;
#pragma unroll
          for (int g = 0; g < 4; ++g) pk[g] = f2bf(vv[g]);
          *(u16x4*)(vt_out + (((size_t)(bb * 16 + hh)) * 64 + dd) * 2048 + tt0) = pk;
        } else {
          u16* base = (which == 0) ? q_out : k_out;
#pragma unroll
          for (int g = 0; g < 4; ++g) {
            float v = vv[g];
            if (which == 0) v *= QSCALE;
            base[(((size_t)(bb * 16 + hh)) * 2048 + tt0 + g) * 64 + dd] = f2bf(v);
          }
        }
      } else {
#pragma unroll
        for (int g = 0; g < 4; ++g)
          outp[(size_t)(row0 + g) * 1024 + col] = vv[g];
      }
    }
  }
}

// ---------------- flash attention v6 ----------------
// grid (8, B*H), 256 thr. Block bx handles FOUR 64-row q-chunks {bx,15-bx,16+bx,31-bx}
// (Sum n = 66, balanced). Wave w owns rows [16w,16w+16) of EACH chunk -> 64 q-rows/wave:
// kf/vf LDS reads amortized over 64 q-rows. S^T=mfma(kf,qf), static-max softmax,
// l via ones-MFMA, O^T=mfma(vf,pa). Dbuf K/V staging, 1 barrier + 1 fence/tile.
// LDS = 16K + 16K + 32K(Ps) = 64 KiB -> 2 blocks/CU.
__global__ __launch_bounds__(256, 2) void k_attn(const u16* __restrict__ qg,
                                                 const u16* __restrict__ kg,
                                                 const u16* __restrict__ vtg,
                                                 u16* __restrict__ yg) {
  __shared__ u16 Ks[2][64 * 64];   // [buf][row][8chunk ^ (row&7)]
  __shared__ u16 Vs[2][64 * 64];   // [buf][d]  [8chunk ^ (d&7)]
  __shared__ u16 Ps[4][64 * 64];   // [wave][c*16 + r][col ^ ((r&7)*8)]

  int bh = blockIdx.y, bb = bh >> 4, hh = bh & 15;
  int bx = blockIdx.x;  // 0..7
  int tid = threadIdx.x, w = tid >> 6, l = tid & 63;
  int r = l & 15, qd = l >> 4;
  int psw = (r & 7) * 8;

  const int chunk[4] = {bx, 15 - bx, 16 + bx, 31 - bx};
  const int nend[4]  = {bx + 1, 16 - bx, 17 + bx, 32 - bx};
  int nmax = 32 - bx;
  int qloc = w * 16 + r;  // within-chunk q row owned by lane r

  // Q b-fragments (q pre-scaled by 1/8*log2e at GEMM0 epilogue)
  s16x8 qf[4][2];
#pragma unroll
  for (int c = 0; c < 4; ++c) {
    int qbase = chunk[c] * 64 + w * 16;
#pragma unroll
    for (int s = 0; s < 2; ++s)
      qf[c][s] = *(const s16x8*)(qg + ((size_t)bh * 2048 + qbase + r) * 64 + s * 32 + qd * 8);
  }

  s16x8 onesf;
#pragma unroll
  for (int e = 0; e < 8; ++e) onesf[e] = (short)0x3F80;  // bf16 1.0

  f32x4 o[4][4] = {};    // O^T: o[c][j][g] = O[q=qbase_c + r][d = 16j + 4qd + g]
  f32x4 lacc[4] = {};    // ones-MFMA row-sum

  // staging lane geometry
  int rl = l >> 3;
  int cg = (l & 7) ^ rl;
  const u16* kbase = kg + (size_t)bh * 2048 * 64;
  const u16* vbase = vtg + (size_t)bh * 64 * 2048;

  auto stage = [&](int kt, int buf) {
    int kk0 = kt * 64;
#pragma unroll
    for (int p = 0; p < 2; ++p) {
      int row = p * 32 + w * 8 + rl;
      gll16(kbase + ((size_t)(kk0 + row)) * 64 + cg * 8, Ks[buf] + p * 2048 + w * 512);
      gll16(vbase + (size_t)row * 2048 + kk0 + cg * 8, Vs[buf] + p * 2048 + w * 512);
    }
  };

  stage(0, 0);
  __syncthreads();  // vmcnt drained -> buf0 visible

  for (int kt = 0; kt < nmax; ++kt) {
    int cur = kt & 1;
    if (kt + 1 < nmax) stage(kt + 1, cur ^ 1);  // prefetch flies under compute

    // ---- QK^T for all active chunks; kf read once, feeds up to 4 chunks ----
    f32x4 sacc[4][4];
#pragma unroll
    for (int c = 0; c < 4; ++c)
      if (kt < nend[c])
#pragma unroll
        for (int j = 0; j < 4; ++j) sacc[c][j] = f32x4{0.f, 0.f, 0.f, 0.f};
#pragma unroll
    for (int s = 0; s < 2; ++s) {
#pragma unroll
      for (int j = 0; j < 4; ++j) {
        s16x8 kf = *(const s16x8*)(Ks[cur] + (16 * j + r) * 64 + ((s * 4 + qd) ^ (r & 7)) * 8);
#pragma unroll
        for (int c = 0; c < 4; ++c)
          if (kt < nend[c]) sacc[c][j] = mfma16(kf, qf[c][s], sacc[c][j]);
      }
    }

    // ---- softmax + P store (chunk-private Ps rows -> no WAR fence needed) ----
#pragma unroll
    for (int c = 0; c < 4; ++c) {
      if (kt >= nend[c]) continue;
      bool needMask = (kt == chunk[c]);  // diagonal tile
#pragma unroll
      for (int j = 0; j < 4; ++j) {
        float p0, p1, p2, p3;  // k-local = 16j + 4qd + g
        if (needMask) {
          int kb0 = 16 * j + 4 * qd;
          p0 = (kb0 + 0 > qloc) ? 0.f : __builtin_amdgcn_exp2f(sacc[c][j][0]);
          p1 = (kb0 + 1 > qloc) ? 0.f : __builtin_amdgcn_exp2f(sacc[c][j][1]);
          p2 = (kb0 + 2 > qloc) ? 0.f : __builtin_amdgcn_exp2f(sacc[c][j][2]);
          p3 = (kb0 + 3 > qloc) ? 0.f : __builtin_amdgcn_exp2f(sacc[c][j][3]);
        } else {
          p0 = __builtin_amdgcn_exp2f(sacc[c][j][0]);
          p1 = __builtin_amdgcn_exp2f(sacc[c][j][1]);
          p2 = __builtin_amdgcn_exp2f(sacc[c][j][2]);
          p3 = __builtin_amdgcn_exp2f(sacc[c][j][3]);
        }
        uint2 pk;
        pk.x = pk_trunc(p1, p0);
        pk.y = pk_trunc(p3, p2);
        *(uint2*)(Ps[w] + (c * 16 + r) * 64 + ((j * 16 + qd * 4) ^ psw)) = pk;
      }
    }
    lds_fence();  // P stores visible to own wave's reads

    // ---- PV burst: vf read once per (s,j), shared by all active chunks ----
#pragma unroll
    for (int s = 0; s < 2; ++s) {
      s16x8 pa[4];
#pragma unroll
      for (int c = 0; c < 4; ++c)
        if (kt < nend[c]) {
          pa[c] = *(const s16x8*)(Ps[w] + (c * 16 + r) * 64 + ((s * 32 + qd * 8) ^ psw));
          lacc[c] = mfma16(onesf, pa[c], lacc[c]);
        }
#pragma unroll
      for (int j = 0; j < 4; ++j) {
        s16x8 vf = *(const s16x8*)(Vs[cur] + (16 * j + r) * 64 + ((s * 4 + qd) ^ (r & 7)) * 8);
#pragma unroll
        for (int c = 0; c < 4; ++c)
          if (kt < nend[c]) o[c][j] = mfma16(vf, pa[c], o[c][j]);
      }
    }
    __syncthreads();  // all reads of buf[cur] done + prefetch into buf[cur^1] landed
  }

  // epilogue: lane (r,qd), chunk c: y[q = qbase_c + r][d = 16j + 4qd + g], packed x4
#pragma unroll
  for (int c = 0; c < 4; ++c) {
    int qbase = chunk[c] * 64 + w * 16;
    float inv = 1.0f / lacc[c][0];
    size_t rowoff = ((size_t)bb * 2048 + qbase + r) * 1024 + hh * 64;
#pragma unroll
    for (int j = 0; j < 4; ++j) {
      u16x4 yv;
      yv[0] = f2bf(o[c][j][0] * inv);
      yv[1] = f2bf(o[c][j][1] * inv);
      yv[2] = f2bf(o[c][j][2] * inv);
      yv[3] = f2bf(o[c][j][3] * inv);
      *(u16x4*)(yg + rowoff + 16 * j + 4 * qd) = yv;
    }
  }
}

// ---------------- launch ----------------
extern "C" void kernel_launch(void* const* d_in, const int* in_sizes, int n_in,
                              void* d_out, int out_size, void* d_ws, size_t ws_size,
                              hipStream_t stream) {
  const float* x      = (const float*)d_in[0];
  const float* w_attn = (const float*)d_in[1];
  const float* b_attn = (const float*)d_in[2];
  const float* w_proj = (const float*)d_in[3];
  const float* b_proj = (const float*)d_in[4];
  float* out = (float*)d_out;

  char* ws = (char*)d_ws;
  size_t off = 0;
  auto alloc = [&](size_t bytes) -> void* {
    void* p = ws + off;
    off += (bytes + 255) & ~(size_t)255;
    return p;
  };
  const size_t BT = 8192, C = 1024;
  u16* xb  = (u16*)alloc(BT * C * 2);          // x bf16; reused as y
  u16* waT = (u16*)alloc(3072 * 1024 * 2);
  u16* wpT = (u16*)alloc(1024 * 1024 * 2);
  u16* qb  = (u16*)alloc(BT * C * 2);          // [BH][T][D], q pre-scaled
  u16* kb  = (u16*)alloc(BT * C * 2);          // [BH][T][D]
  u16* vtb = (u16*)alloc(BT * C * 2);          // [BH][D][T] (written by GEMM0 directly)
  (void)ws_size; (void)in_sizes; (void)n_in; (void)out_size;

  k_convert_x<<<4096, 256, 0, stream>>>(x, xb);
  k_transpose_w<<<dim3(96, 32), 256, 0, stream>>>(w_attn, waT, 1024, 3072);
  k_transpose_w<<<dim3(32, 32), 256, 0, stream>>>(w_proj, wpT, 1024, 1024);
  k_gemm<0><<<1536, 256, 0, stream>>>(xb, waT, b_attn, nullptr, qb, kb, vtb, 1024, 32);
  k_attn<<<dim3(8, 64), 256, 0, stream>>>(qb, kb, vtb, xb /* y reuses xb */);
  k_gemm<1><<<512, 256, 0, stream>>>(xb, wpT, b_proj, out, nullptr, nullptr, nullptr, 1024, 32);
}